// Round 3
// baseline (505.685 us; speedup 1.0000x reference)
//
#include <hip/hip_runtime.h>

// Additive (Bahdanau) attention, fused single-pass over encoder_outputs.
// enc: (32, 8192, 256) fp32 is the only big tensor (256 MiB) -> read ONCE.
//   prep:   B16frag = f16(We^T) in MFMA-fragment order (128 KiB), qb[b,k] = b[k] + hidden[b]·Wh[k,:]
//   main:   per block = 128 rows of one batch: MFMA f16 GEMM (enc·We^T) -> +qb -> tanh -> ·v -> logits
//           local softmax stats (m,l) + unnormalized partial context from register-resident enc
//   finish: merge 64 chunks/batch -> context (32x256) and attn weights (32x8192)
//
// History:
//  R1: launch_bounds(512,4) => 4 blocks/CU => 64-VGPR cap => A spilled (WRITE 268MB, 226us)
//  R2: (512,2) => 128-VGPR cap, but 32 rows/wave needs ~130+ live => still ~22 dw/thread spill
//      (WRITE 47MB), latency-bound at 1TB/s, 209us.
//  R3: 16 rows/wave => A=32 VGPR, peak live ~90 => no spill, more load-landing regs.

typedef _Float16 f16x8 __attribute__((ext_vector_type(8)));
typedef float    f32x4 __attribute__((ext_vector_type(4)));

__device__ __forceinline__ float fast_tanh(float x){
  x = fminf(15.f, fmaxf(-15.f, x));
  float e = __expf(2.f * x);
  return (e - 1.f) * __builtin_amdgcn_rcpf(e + 1.f);
}

// ---------------- prep ----------------
__global__ void prep_kernel(const float* __restrict__ hidden, const float* __restrict__ W,
                            const float* __restrict__ bias, _Float16* __restrict__ Bfrag,
                            float* __restrict__ qb)
{
  int blk = blockIdx.x;
  if (blk < 256){
    int tid  = blk * 256 + threadIdx.x;      // 0..65535
    int j    = tid & 7;
    int lane = (tid >> 3) & 63;
    int kc   = (tid >> 9) & 7;
    int nt   = tid >> 12;
    int lc   = lane & 15, q = lane >> 4;
    int row  = nt * 16 + lc;                 // output-k index (B's n)
    int col  = 256 + kc * 32 + q * 8 + j;    // W column (h + 256)
    Bfrag[tid] = (_Float16)W[row * 512 + col];
  } else {
    int b = blk - 256;
    int k = threadIdx.x;
    const float4* hp = (const float4*)(hidden + b * 256);
    const float4* wp = (const float4*)(W + k * 512);
    float s = 0.f;
    for (int i = 0; i < 64; i++){
      float4 h4 = hp[i], w4 = wp[i];
      s += h4.x * w4.x + h4.y * w4.y + h4.z * w4.z + h4.w * w4.w;
    }
    qb[b * 256 + k] = s + bias[k];
  }
}

// ---------------- main ----------------
// grid = 2048 (32 b x 64 chunks), block = 512 (8 waves x 16 rows = 128 rows/block)
__global__ __launch_bounds__(512, 2) void attn_main(
    const float* __restrict__ enc, const _Float16* __restrict__ Bfrag,
    const float* __restrict__ qb, const float* __restrict__ v,
    float* __restrict__ logits, float* __restrict__ P,
    float* __restrict__ mw, float* __restrict__ lw)
{
  __shared__ _Float16 Bs[16384];   // one quarter of B (4 n-tiles), 32 KiB
  __shared__ float sl[128];        // logits, then unnormalized weights
  __shared__ float Pl[256];        // partial context accumulator (k-dim)
  __shared__ float red[16];

  const int b = blockIdx.x >> 6, chunk = blockIdx.x & 63;
  const int tid = threadIdx.x, wv = tid >> 6, lane = tid & 63;
  const int q = lane >> 4, lc = lane & 15;
  const int rowBase = b * 8192 + chunk * 128;
  const int waveRow = wv * 16;

  if (tid < 256) Pl[tid] = 0.f;

  // This wave's 16 enc rows as f16 A-fragments (register resident, 32 VGPRs).
  // A[m = lane&15][k = (lane>>4)*8 + j], k-chunk kc covers k in [kc*32, kc*32+32).
  f16x8 A[8];
  {
    const float* rp = enc + (size_t)(rowBase + waveRow + lc) * 256 + q * 8;
    #pragma unroll
    for (int kc = 0; kc < 8; kc++){
      const float4* p = (const float4*)(rp + kc * 32);
      float4 x0 = p[0], x1 = p[1];
      f16x8 af;
      af[0] = (_Float16)x0.x; af[1] = (_Float16)x0.y; af[2] = (_Float16)x0.z; af[3] = (_Float16)x0.w;
      af[4] = (_Float16)x1.x; af[5] = (_Float16)x1.y; af[6] = (_Float16)x1.z; af[7] = (_Float16)x1.w;
      A[kc] = af;
    }
  }

  float plog[4] = {0, 0, 0, 0};
  const float* qbB = qb + b * 256;

  for (int h = 0; h < 4; h++){
    __syncthreads();
    { // stage B quarter (n-tiles h*4 .. h*4+3) into LDS, fragment order
      const f16x8* src = (const f16x8*)(Bfrag + h * 16384);
      f16x8* dst = (f16x8*)Bs;
      #pragma unroll
      for (int i = 0; i < 4; i++) dst[tid + i * 512] = src[tid + i * 512];
    }
    __syncthreads();
    #pragma unroll
    for (int ntl = 0; ntl < 4; ntl++){
      const int nt = h * 4 + ntl;
      f32x4 acc = {0, 0, 0, 0};
      const f16x8* bp = ((const f16x8*)Bs) + ntl * 512 + lane;
      #pragma unroll
      for (int kc = 0; kc < 8; kc++){
        f16x8 bf = bp[kc * 64];
        acc = __builtin_amdgcn_mfma_f32_16x16x32_f16(A[kc], bf, acc, 0, 0, 0);
      }
      // C/D: col = lane&15 (+nt*16), row = (lane>>4)*4 + r
      const int col = nt * 16 + lc;
      const float qv = qbB[col], vv = v[col];
      #pragma unroll
      for (int r = 0; r < 4; r++)
        plog[r] += fast_tanh(acc[r] + qv) * vv;
    }
  }

  // reduce logit partials across the 16 columns (lanes sharing q)
  #pragma unroll
  for (int r = 0; r < 4; r++){
    float s = plog[r];
    s += __shfl_xor(s, 1); s += __shfl_xor(s, 2);
    s += __shfl_xor(s, 4); s += __shfl_xor(s, 8);
    plog[r] = s;
  }
  if (lc == 0){
    #pragma unroll
    for (int r = 0; r < 4; r++){
      int rl = waveRow + q * 4 + r;
      sl[rl] = plog[r];
      logits[rowBase + rl] = plog[r];
    }
  }
  __syncthreads();

  // block-local softmax stats over the 128 logits (2 waves participate)
  if (tid < 128){
    float x = sl[tid], m = x;
    for (int o = 1; o < 64; o <<= 1) m = fmaxf(m, __shfl_xor(m, o));
    if (lane == 0) red[wv] = m;
  }
  __syncthreads();
  if (tid == 0) red[8] = fmaxf(red[0], red[1]);
  __syncthreads();
  const float M = red[8];
  if (tid < 128){
    float e = __expf(sl[tid] - M);
    sl[tid] = e;                       // unnormalized weight
    float s2 = e;
    for (int o = 1; o < 64; o <<= 1) s2 += __shfl_xor(s2, o);
    if (lane == 0) red[wv] = s2;
  }
  __syncthreads();
  if (tid == 0){ mw[blockIdx.x] = M; lw[blockIdx.x] = red[0] + red[1]; }

  // partial context from register-resident enc rows: Pl[k] = sum_rows w[row]*enc[row,k]
  const float w0 = sl[waveRow + lc];
  #pragma unroll
  for (int kc = 0; kc < 8; kc++){
    float c8[8];
    #pragma unroll
    for (int j = 0; j < 8; j++)
      c8[j] = w0 * (float)A[kc][j];
    #pragma unroll
    for (int j = 0; j < 8; j++){
      float s = c8[j];
      s += __shfl_xor(s, 1); s += __shfl_xor(s, 2);
      s += __shfl_xor(s, 4); s += __shfl_xor(s, 8);
      c8[j] = s;
    }
    if (lc == 0){
      #pragma unroll
      for (int j = 0; j < 8; j++) atomicAdd(&Pl[kc * 32 + q * 8 + j], c8[j]);
    }
  }
  __syncthreads();
  if (tid < 256) P[(size_t)blockIdx.x * 256 + tid] = Pl[tid];
}

// ---------------- finish ----------------
// grid = 32 (one per batch), block = 256
__global__ void attn_finish(const float* __restrict__ logits, const float* __restrict__ P,
                            const float* __restrict__ mw, const float* __restrict__ lw,
                            float* __restrict__ out)
{
  const int b = blockIdx.x, t = threadIdx.x;
  __shared__ float sm[64], sw[64];
  if (t < 64){ sm[t] = mw[b * 64 + t]; sw[t] = lw[b * 64 + t]; }
  __syncthreads();
  float M = -1e30f;
  for (int i = 0; i < 64; i++) M = fmaxf(M, sm[i]);
  float L = 0.f;
  for (int i = 0; i < 64; i++) L += sw[i] * __expf(sm[i] - M);
  const float inv = 1.f / L;
  // context (t = k index)
  float c = 0.f;
  for (int ch = 0; ch < 64; ch++) c += __expf(sm[ch] - M) * P[(size_t)(b * 64 + ch) * 256 + t];
  out[b * 256 + t] = c * inv;
  // attention weights
  const float* lg = logits + (size_t)b * 8192;
  float* ao = out + 8192 + (size_t)b * 8192;
  for (int s = t; s < 8192; s += 256) ao[s] = __expf(lg[s] - M) * inv;
}

extern "C" void kernel_launch(void* const* d_in, const int* in_sizes, int n_in,
                              void* d_out, int out_size, void* d_ws, size_t ws_size,
                              hipStream_t stream)
{
  const float* hidden = (const float*)d_in[0];   // (1,32,256)
  const float* enc    = (const float*)d_in[1];   // (32,8192,256)
  const float* W      = (const float*)d_in[2];   // (256,512)
  const float* bias   = (const float*)d_in[3];   // (256,)
  const float* v      = (const float*)d_in[4];   // (256,)
  float* out = (float*)d_out;

  char* ws = (char*)d_ws;
  _Float16* Bfrag = (_Float16*)ws;                                      // 128 KiB
  float* qb     = (float*)(ws + (128 << 10));                           // 32 KiB
  float* logits = (float*)(ws + (160 << 10));                           // 1 MiB
  float* P      = (float*)(ws + (160 << 10) + (1 << 20));               // 2 MiB (2048*256*4)
  float* mw     = (float*)(ws + (160 << 10) + (3 << 20));               // 8 KiB
  float* lw     = (float*)(ws + (160 << 10) + (3 << 20) + (8 << 10));   // 8 KiB

  prep_kernel<<<288, 256, 0, stream>>>(hidden, W, bias, Bfrag, qb);
  attn_main<<<2048, 512, 0, stream>>>(enc, Bfrag, qb, v, logits, P, mw, lw);
  attn_finish<<<32, 256, 0, stream>>>(logits, P, mw, lw, out);
}

// Round 4
// 459.569 us; speedup vs baseline: 1.1003x; 1.1003x over previous
//
#include <hip/hip_runtime.h>

// Additive (Bahdanau) attention, fused single-pass over encoder_outputs.
// enc: (32, 8192, 256) fp32 is the only big tensor (256 MiB) -> read ONCE.
//   prep:   B16frag = f16(We^T) in MFMA-fragment order (128 KiB), qb[b,k] = b[k] + hidden[b]·Wh[k,:]
//   main:   per block = 64 rows of one batch: MFMA f16 GEMM (enc·We^T) -> +qb -> tanh -> ·v -> logits
//           local softmax stats (m,l) + unnormalized partial context from register-resident enc
//   finish: merge 128 chunks/batch -> context (32x256) and attn weights (32x8192)
//
// History:
//  R1: launch_bounds(512,4) => 64-VGPR cap => A spilled (WRITE 268MB), 226us
//  R2: (512,2) => 128 VGPR but 32 rows/wave still spills ~22dw/thr (WRITE 47MB), 209us
//  R3: 16 rows/wave => no spill (WRITE 3MB, VGPR 80) but STILL 224us; occupancy 23.8%
//      ~= 2 waves/SIMD; runtime invariant ~220us across 548->142MB traffic => latency-bound,
//      occupancy capped by launch_bounds' waves-per-EU constraint.
//  R4: drop min-occupancy bound, block=256 (4 waves), LDS 35->17.5KB => target 20+ waves/CU.

typedef _Float16 f16x8 __attribute__((ext_vector_type(8)));
typedef float    f32x4 __attribute__((ext_vector_type(4)));

__device__ __forceinline__ float fast_tanh(float x){
  x = fminf(15.f, fmaxf(-15.f, x));
  float e = __expf(2.f * x);
  return (e - 1.f) * __builtin_amdgcn_rcpf(e + 1.f);
}

// ---------------- prep ----------------
__global__ void prep_kernel(const float* __restrict__ hidden, const float* __restrict__ W,
                            const float* __restrict__ bias, _Float16* __restrict__ Bfrag,
                            float* __restrict__ qb)
{
  int blk = blockIdx.x;
  if (blk < 256){
    int tid  = blk * 256 + threadIdx.x;      // 0..65535
    int j    = tid & 7;
    int lane = (tid >> 3) & 63;
    int kc   = (tid >> 9) & 7;
    int nt   = tid >> 12;
    int lc   = lane & 15, q = lane >> 4;
    int row  = nt * 16 + lc;                 // output-k index (B's n)
    int col  = 256 + kc * 32 + q * 8 + j;    // W column (h + 256)
    Bfrag[tid] = (_Float16)W[row * 512 + col];
  } else {
    int b = blk - 256;
    int k = threadIdx.x;
    const float4* hp = (const float4*)(hidden + b * 256);
    const float4* wp = (const float4*)(W + k * 512);
    float s = 0.f;
    for (int i = 0; i < 64; i++){
      float4 h4 = hp[i], w4 = wp[i];
      s += h4.x * w4.x + h4.y * w4.y + h4.z * w4.z + h4.w * w4.w;
    }
    qb[b * 256 + k] = s + bias[k];
  }
}

// ---------------- main ----------------
// grid = 4096 (32 b x 128 chunks), block = 256 (4 waves x 16 rows = 64 rows/block)
__global__ __launch_bounds__(256) void attn_main(
    const float* __restrict__ enc, const _Float16* __restrict__ Bfrag,
    const float* __restrict__ qb, const float* __restrict__ v,
    float* __restrict__ logits, float* __restrict__ P,
    float* __restrict__ mw, float* __restrict__ lw)
{
  __shared__ _Float16 Bs[8192];    // 2 n-tiles of B, 16 KiB
  __shared__ float sl[64];         // logits, then unnormalized weights
  __shared__ float Pl[256];        // partial context accumulator (k-dim)

  const int b = blockIdx.x >> 7, chunk = blockIdx.x & 127;
  const int tid = threadIdx.x, wv = tid >> 6, lane = tid & 63;
  const int q = lane >> 4, lc = lane & 15;
  const int rowBase = b * 8192 + chunk * 64;
  const int waveRow = wv * 16;

  Pl[tid] = 0.f;

  // This wave's 16 enc rows as f16 A-fragments (register resident, 32 VGPRs).
  // A[m = lane&15][k = (lane>>4)*8 + j], k-chunk kc covers k in [kc*32, kc*32+32).
  f16x8 A[8];
  {
    const float* rp = enc + (size_t)(rowBase + waveRow + lc) * 256 + q * 8;
    #pragma unroll
    for (int kc = 0; kc < 8; kc++){
      const float4* p = (const float4*)(rp + kc * 32);
      float4 x0 = p[0], x1 = p[1];
      f16x8 af;
      af[0] = (_Float16)x0.x; af[1] = (_Float16)x0.y; af[2] = (_Float16)x0.z; af[3] = (_Float16)x0.w;
      af[4] = (_Float16)x1.x; af[5] = (_Float16)x1.y; af[6] = (_Float16)x1.z; af[7] = (_Float16)x1.w;
      A[kc] = af;
    }
  }

  float plog[4] = {0, 0, 0, 0};
  const float* qbB = qb + b * 256;

  for (int h = 0; h < 8; h++){
    __syncthreads();
    { // stage 2 n-tiles (h*2, h*2+1) into LDS, fragment order (1024 f16x8)
      const f16x8* src = (const f16x8*)(Bfrag + h * 8192);
      f16x8* dst = (f16x8*)Bs;
      #pragma unroll
      for (int i = 0; i < 4; i++) dst[tid + i * 256] = src[tid + i * 256];
    }
    __syncthreads();
    #pragma unroll
    for (int ntl = 0; ntl < 2; ntl++){
      const int nt = h * 2 + ntl;
      f32x4 acc = {0, 0, 0, 0};
      const f16x8* bp = ((const f16x8*)Bs) + ntl * 512 + lane;
      #pragma unroll
      for (int kc = 0; kc < 8; kc++){
        f16x8 bf = bp[kc * 64];
        acc = __builtin_amdgcn_mfma_f32_16x16x32_f16(A[kc], bf, acc, 0, 0, 0);
      }
      // C/D: col = lane&15 (+nt*16), row = (lane>>4)*4 + r
      const int col = nt * 16 + lc;
      const float qv = qbB[col], vv = v[col];
      #pragma unroll
      for (int r = 0; r < 4; r++)
        plog[r] += fast_tanh(acc[r] + qv) * vv;
    }
  }

  // reduce logit partials across the 16 columns (lanes sharing q)
  #pragma unroll
  for (int r = 0; r < 4; r++){
    float s = plog[r];
    s += __shfl_xor(s, 1); s += __shfl_xor(s, 2);
    s += __shfl_xor(s, 4); s += __shfl_xor(s, 8);
    plog[r] = s;
  }
  if (lc == 0){
    #pragma unroll
    for (int r = 0; r < 4; r++){
      int rl = waveRow + q * 4 + r;
      sl[rl] = plog[r];
      logits[rowBase + rl] = plog[r];
    }
  }
  __syncthreads();

  // block-local softmax stats over the 64 logits (wave 0 only)
  if (tid < 64){
    float x = sl[tid];
    float m = x;
    for (int o = 1; o < 64; o <<= 1) m = fmaxf(m, __shfl_xor(m, o));
    float e = __expf(x - m);
    sl[tid] = e;                       // unnormalized weight
    float s2 = e;
    for (int o = 1; o < 64; o <<= 1) s2 += __shfl_xor(s2, o);
    if (tid == 0){ mw[blockIdx.x] = m; lw[blockIdx.x] = s2; }
  }
  __syncthreads();

  // partial context from register-resident enc rows: Pl[k] = sum_rows w[row]*enc[row,k]
  const float w0 = sl[waveRow + lc];
  #pragma unroll
  for (int kc = 0; kc < 8; kc++){
    float c8[8];
    #pragma unroll
    for (int j = 0; j < 8; j++)
      c8[j] = w0 * (float)A[kc][j];
    #pragma unroll
    for (int j = 0; j < 8; j++){
      float s = c8[j];
      s += __shfl_xor(s, 1); s += __shfl_xor(s, 2);
      s += __shfl_xor(s, 4); s += __shfl_xor(s, 8);
      c8[j] = s;
    }
    if (lc == 0){
      #pragma unroll
      for (int j = 0; j < 8; j++) atomicAdd(&Pl[kc * 32 + q * 8 + j], c8[j]);
    }
  }
  __syncthreads();
  P[(size_t)blockIdx.x * 256 + tid] = Pl[tid];
}

// ---------------- finish ----------------
// grid = 32 (one per batch), block = 256
__global__ void attn_finish(const float* __restrict__ logits, const float* __restrict__ P,
                            const float* __restrict__ mw, const float* __restrict__ lw,
                            float* __restrict__ out)
{
  const int b = blockIdx.x, t = threadIdx.x;
  __shared__ float sm[128], sw[128], se[128], sM[1], sL[1];
  if (t < 128){ sm[t] = mw[b * 128 + t]; sw[t] = lw[b * 128 + t]; }
  __syncthreads();
  if (t == 0){
    float M = -1e30f;
    for (int i = 0; i < 128; i++) M = fmaxf(M, sm[i]);
    sM[0] = M;
  }
  __syncthreads();
  const float M = sM[0];
  if (t < 128) se[t] = __expf(sm[t] - M);
  __syncthreads();
  if (t == 0){
    float L = 0.f;
    for (int i = 0; i < 128; i++) L += sw[i] * se[i];
    sL[0] = L;
  }
  __syncthreads();
  const float inv = 1.f / sL[0];
  // context (t = k index)
  float c = 0.f;
  for (int ch = 0; ch < 128; ch++) c += se[ch] * P[(size_t)(b * 128 + ch) * 256 + t];
  out[b * 256 + t] = c * inv;
  // attention weights
  const float* lg = logits + (size_t)b * 8192;
  float* ao = out + 8192 + (size_t)b * 8192;
  for (int s = t; s < 8192; s += 256) ao[s] = __expf(lg[s] - M) * inv;
}

extern "C" void kernel_launch(void* const* d_in, const int* in_sizes, int n_in,
                              void* d_out, int out_size, void* d_ws, size_t ws_size,
                              hipStream_t stream)
{
  const float* hidden = (const float*)d_in[0];   // (1,32,256)
  const float* enc    = (const float*)d_in[1];   // (32,8192,256)
  const float* W      = (const float*)d_in[2];   // (256,512)
  const float* bias   = (const float*)d_in[3];   // (256,)
  const float* v      = (const float*)d_in[4];   // (256,)
  float* out = (float*)d_out;

  char* ws = (char*)d_ws;
  _Float16* Bfrag = (_Float16*)ws;                                      // 128 KiB
  float* qb     = (float*)(ws + (128 << 10));                           // 32 KiB
  float* logits = (float*)(ws + (160 << 10));                           // 1 MiB
  float* P      = (float*)(ws + (160 << 10) + (1 << 20));               // 4 MiB (4096*256*4)
  float* mw     = (float*)(ws + (160 << 10) + (5 << 20));               // 16 KiB
  float* lw     = (float*)(ws + (160 << 10) + (5 << 20) + (16 << 10));  // 16 KiB

  prep_kernel<<<288, 256, 0, stream>>>(hidden, W, bias, Bfrag, qb);
  attn_main<<<4096, 256, 0, stream>>>(enc, Bfrag, qb, v, logits, P, mw, lw);
  attn_finish<<<32, 256, 0, stream>>>(logits, P, mw, lw, out);
}

// Round 5
// 414.418 us; speedup vs baseline: 1.2202x; 1.1090x over previous
//
#include <hip/hip_runtime.h>

// Additive (Bahdanau) attention, fused single-pass over encoder_outputs.
// enc: (32, 8192, 256) fp32 is the only big tensor (256 MiB).
//   prep:   B16frag = f16(We^T) in MFMA-fragment order (128 KiB), qb[b,k] = b[k] + hidden[b]·Wh[k,:]
//   main:   per block = 64 rows of one batch. R5 structure: B in per-wave REGISTERS
//           (wave w owns n-tiles {2w,2w+1}, loaded once), A staged once in LDS
//           (fragment order). 4 barriers/block instead of 18. Context via coalesced
//           L2-hot enc re-read (thread-per-k), replacing the 256-shuffle reduction.
//   finish: merge 128 chunks/batch -> context (32x256) and attn weights (32x8192)
//
// History:
//  R1: launch_bounds(512,4) => 64-VGPR cap => A spilled (WRITE 268MB), 226us
//  R2: (512,2) => 128 VGPR, 32 rows/wave still spills (WRITE 47MB), 209us
//  R3: 16 rows/wave, no spill (VGPR 80) but 224us; occupancy 24% => latency-bound
//  R4: block=256, no min-occupancy bound: 191us, occupancy only 33%; runtime invariant
//      vs traffic => per-block serial path: 18 barriers + L2-latency staging inside each
//      + ~600-op shuffle epilogue. R5 restructures to kill all three.

typedef _Float16 f16x8 __attribute__((ext_vector_type(8)));
typedef _Float16 f16x4 __attribute__((ext_vector_type(4)));
typedef float    f32x4 __attribute__((ext_vector_type(4)));

__device__ __forceinline__ float fast_tanh(float x){
  x = fminf(15.f, fmaxf(-15.f, x));
  float e = __expf(2.f * x);
  return (e - 1.f) * __builtin_amdgcn_rcpf(e + 1.f);
}

// ---------------- prep ----------------
__global__ void prep_kernel(const float* __restrict__ hidden, const float* __restrict__ W,
                            const float* __restrict__ bias, _Float16* __restrict__ Bfrag,
                            float* __restrict__ qb)
{
  int blk = blockIdx.x;
  if (blk < 256){
    int tid  = blk * 256 + threadIdx.x;      // 0..65535
    int j    = tid & 7;
    int lane = (tid >> 3) & 63;
    int kc   = (tid >> 9) & 7;
    int nt   = tid >> 12;
    int lc   = lane & 15, q = lane >> 4;
    int row  = nt * 16 + lc;                 // output-k index (B's n)
    int col  = 256 + kc * 32 + q * 8 + j;    // W column (h + 256)
    Bfrag[tid] = (_Float16)W[row * 512 + col];
  } else {
    int b = blk - 256;
    int k = threadIdx.x;
    const float4* hp = (const float4*)(hidden + b * 256);
    const float4* wp = (const float4*)(W + k * 512);
    float s = 0.f;
    for (int i = 0; i < 64; i++){
      float4 h4 = hp[i], w4 = wp[i];
      s += h4.x * w4.x + h4.y * w4.y + h4.z * w4.z + h4.w * w4.w;
    }
    qb[b * 256 + k] = s + bias[k];
  }
}

// ---------------- main ----------------
// grid = 4096 (32 b x 128 chunks), block = 512 (8 waves; 64 rows/block; wave w owns
// k-cols [w*32, w*32+32) for ALL 64 rows)
__global__ __launch_bounds__(512) void attn_main(
    const float* __restrict__ enc, const _Float16* __restrict__ Bfrag,
    const float* __restrict__ qb, const float* __restrict__ v,
    float* __restrict__ logits, float* __restrict__ P,
    float* __restrict__ mw, float* __restrict__ lw)
{
  __shared__ _Float16 Af[16384];   // 64 rows x 256 cols, MFMA-A fragment order, 32 KiB
  __shared__ float plg[8][64];     // per-wave partial logits
  __shared__ float sw[64];         // unnormalized softmax weights
  __shared__ float Pl2[2][256];    // context partials (row-halves)

  const int b = blockIdx.x >> 7, chunk = blockIdx.x & 127;
  const int tid = threadIdx.x, wv = tid >> 6, lane = tid & 63;
  const int q = lane >> 4, lc = lane & 15;
  const int rowBase = b * 8192 + chunk * 64;

  // ---- Phase 0a: per-wave B fragments (2 n-tiles, 64 VGPRs), loaded once ----
  const int nt0 = wv * 2;
  f16x8 Breg[2][8];
  {
    const f16x8* Bsrc = (const f16x8*)Bfrag;
    #pragma unroll
    for (int ntl = 0; ntl < 2; ntl++)
      #pragma unroll
      for (int kc = 0; kc < 8; kc++)
        Breg[ntl][kc] = Bsrc[((nt0 + ntl) * 8 + kc) * 64 + lane];
  }
  float qv[2], vv[2];
  #pragma unroll
  for (int ntl = 0; ntl < 2; ntl++){
    int col = (nt0 + ntl) * 16 + lc;
    qv[ntl] = qb[b * 256 + col];
    vv[ntl] = v[col];
  }

  // ---- Phase 0b: stage 64 enc rows into LDS in A-fragment order ----
  // thread t: row r = t>>3, k-chunk kc = t&7 (32 cols = 8 float4)
  {
    const int r = tid >> 3, kc = tid & 7;
    const float4* src = (const float4*)(enc + (size_t)(rowBase + r) * 256 + kc * 32);
    const int mt = r >> 4, lcr = r & 15;
    #pragma unroll
    for (int i = 0; i < 8; i++){
      float4 x = src[i];
      f16x4 h4;
      h4[0] = (_Float16)x.x; h4[1] = (_Float16)x.y;
      h4[2] = (_Float16)x.z; h4[3] = (_Float16)x.w;
      // element (row r, col kc*32 + i*4 + e) -> frag idx (((mt*8+kc)*64 + q*16 + lc)*8 + j)
      int idx = (((mt * 8 + kc) * 64 + (i >> 1) * 16 + lcr) * 8 + (i & 1) * 4);
      *(f16x4*)(&Af[idx]) = h4;
    }
  }
  __syncthreads();

  // ---- Phase 1: GEMM + tanh + partial logits (no barriers inside) ----
  {
    const f16x8* Afp = (const f16x8*)Af;
    #pragma unroll
    for (int mt = 0; mt < 4; mt++){
      f32x4 acc0 = {0, 0, 0, 0}, acc1 = {0, 0, 0, 0};
      #pragma unroll
      for (int kc = 0; kc < 8; kc++){
        f16x8 af = Afp[(mt * 8 + kc) * 64 + lane];
        acc0 = __builtin_amdgcn_mfma_f32_16x16x32_f16(af, Breg[0][kc], acc0, 0, 0, 0);
        acc1 = __builtin_amdgcn_mfma_f32_16x16x32_f16(af, Breg[1][kc], acc1, 0, 0, 0);
      }
      // C/D: col = lane&15 (this wave's k-col), row = q*4 + r (+mt*16)
      #pragma unroll
      for (int r = 0; r < 4; r++){
        float s = fast_tanh(acc0[r] + qv[0]) * vv[0] + fast_tanh(acc1[r] + qv[1]) * vv[1];
        s += __shfl_xor(s, 1); s += __shfl_xor(s, 2);
        s += __shfl_xor(s, 4); s += __shfl_xor(s, 8);
        if (lc == 0) plg[wv][mt * 16 + q * 4 + r] = s;
      }
    }
  }
  __syncthreads();

  // ---- Phase 2: block softmax over 64 rows (wave 0) ----
  if (tid < 64){
    float x = 0.f;
    #pragma unroll
    for (int w = 0; w < 8; w++) x += plg[w][tid];
    logits[rowBase + tid] = x;
    float m = x;
    for (int o = 1; o < 64; o <<= 1) m = fmaxf(m, __shfl_xor(m, o));
    float e = __expf(x - m);
    sw[tid] = e;
    float s2 = e;
    for (int o = 1; o < 64; o <<= 1) s2 += __shfl_xor(s2, o);
    if (tid == 0){ mw[blockIdx.x] = m; lw[blockIdx.x] = s2; }
  }
  __syncthreads();

  // ---- Phase 3: context partials; coalesced enc re-read (L1/L2-hot) ----
  {
    const int k = tid & 255, h = tid >> 8;        // h = row-half
    const float* ep = enc + (size_t)(rowBase + h * 32) * 256 + k;
    const float* swh = sw + h * 32;
    float s0 = 0.f, s1 = 0.f, s2 = 0.f, s3 = 0.f;
    #pragma unroll
    for (int r4 = 0; r4 < 8; r4++){
      s0 += swh[r4 * 4 + 0] * ep[(size_t)(r4 * 4 + 0) * 256];
      s1 += swh[r4 * 4 + 1] * ep[(size_t)(r4 * 4 + 1) * 256];
      s2 += swh[r4 * 4 + 2] * ep[(size_t)(r4 * 4 + 2) * 256];
      s3 += swh[r4 * 4 + 3] * ep[(size_t)(r4 * 4 + 3) * 256];
    }
    Pl2[h][k] = (s0 + s1) + (s2 + s3);
  }
  __syncthreads();
  if (tid < 256) P[(size_t)blockIdx.x * 256 + tid] = Pl2[0][tid] + Pl2[1][tid];
}

// ---------------- finish ----------------
// grid = 32 (one per batch), block = 256
__global__ void attn_finish(const float* __restrict__ logits, const float* __restrict__ P,
                            const float* __restrict__ mw, const float* __restrict__ lw,
                            float* __restrict__ out)
{
  const int b = blockIdx.x, t = threadIdx.x;
  __shared__ float sm[128], sw[128], se[128], sM[1], sL[1];
  if (t < 128){ sm[t] = mw[b * 128 + t]; sw[t] = lw[b * 128 + t]; }
  __syncthreads();
  if (t == 0){
    float M = -1e30f;
    for (int i = 0; i < 128; i++) M = fmaxf(M, sm[i]);
    sM[0] = M;
  }
  __syncthreads();
  const float M = sM[0];
  if (t < 128) se[t] = __expf(sm[t] - M);
  __syncthreads();
  if (t == 0){
    float L = 0.f;
    for (int i = 0; i < 128; i++) L += sw[i] * se[i];
    sL[0] = L;
  }
  __syncthreads();
  const float inv = 1.f / sL[0];
  // context (t = k index)
  float c = 0.f;
  for (int ch = 0; ch < 128; ch++) c += se[ch] * P[(size_t)(b * 128 + ch) * 256 + t];
  out[b * 256 + t] = c * inv;
  // attention weights
  const float* lg = logits + (size_t)b * 8192;
  float* ao = out + 8192 + (size_t)b * 8192;
  for (int s = t; s < 8192; s += 256) ao[s] = __expf(lg[s] - M) * inv;
}

extern "C" void kernel_launch(void* const* d_in, const int* in_sizes, int n_in,
                              void* d_out, int out_size, void* d_ws, size_t ws_size,
                              hipStream_t stream)
{
  const float* hidden = (const float*)d_in[0];   // (1,32,256)
  const float* enc    = (const float*)d_in[1];   // (32,8192,256)
  const float* W      = (const float*)d_in[2];   // (256,512)
  const float* bias   = (const float*)d_in[3];   // (256,)
  const float* v      = (const float*)d_in[4];   // (256,)
  float* out = (float*)d_out;

  char* ws = (char*)d_ws;
  _Float16* Bfrag = (_Float16*)ws;                                      // 128 KiB
  float* qb     = (float*)(ws + (128 << 10));                           // 32 KiB
  float* logits = (float*)(ws + (160 << 10));                           // 1 MiB
  float* P      = (float*)(ws + (160 << 10) + (1 << 20));               // 4 MiB (4096*256*4)
  float* mw     = (float*)(ws + (160 << 10) + (5 << 20));               // 16 KiB
  float* lw     = (float*)(ws + (160 << 10) + (5 << 20) + (16 << 10));  // 16 KiB

  prep_kernel<<<288, 256, 0, stream>>>(hidden, W, bias, Bfrag, qb);
  attn_main<<<4096, 512, 0, stream>>>(enc, Bfrag, qb, v, logits, P, mw, lw);
  attn_finish<<<32, 256, 0, stream>>>(logits, P, mw, lw, out);
}